// Round 2
// baseline (157.824 us; speedup 1.0000x reference)
//
#include <hip/hip_runtime.h>
#include <stdint.h>

typedef __attribute__((ext_vector_type(4))) float float4v;

#define D 4096
#define R 16
#define NW 192     // adapters
#define LB 1280    // lora rows
#define NBL 256
#define MAXB 32    // max bucket size per split-block (actual max ~7 after mod-4 split)
#define NWAVE 16   // waves per block
#define NSPLIT 4   // blocks per adapter (row-index mod-4 split)

// ---------------- fused: per-adapter A->h->B->y ----------------
// Grid 768 = 192 adapters x 4 row-slices. Block (w,s) handles bucket rows
// with global row index i where (i mod 4)==s. The partition is deterministic,
// so sibling blocks never overlap and ybuf rows keep a unique writer.
// Why split: round-0 counters showed OccupancyPercent=20.6% with 16-wave
// blocks -> makespan dominated by straggler buckets (max ~16 rows vs mean
// 6.7) walked serially. mod-4 split cuts the serial tail ~2.3x and gives a
// 768-block work queue over 256 CUs; at VGPR=48 two blocks co-reside per CU
// (8 waves/SIMD) hiding the per-row load latency.
// XCD swizzle: all 4 siblings of adapter w share bid%8 -> same XCD L2, so
// the 4x A/B re-read is L2-local.
__global__ __launch_bounds__(1024) void fused_kernel(
    const float* __restrict__ x,
    const float* __restrict__ A,
    const float* __restrict__ B,
    const int* __restrict__ xids,
    const int* __restrict__ wids,
    float* __restrict__ ybuf,   // [NBL*4][D]
    float* __restrict__ out)    // [512][D]
{
    const int bid = blockIdx.x;
    const int xcd = bid & 7;          // dispatch round-robin heuristic: bid%8 = XCD
    const int k_  = bid >> 3;         // 0..95
    const int w   = xcd * (NW / 8) + (k_ >> 2);   // adapter, all slices same XCD
    const int s   = k_ & 3;                       // row slice (i mod 4 == s)
    const int t = threadIdx.x;
    const int lane = t & 63;
    const int wave = t >> 6;

    __shared__ int list[MAXB];
    __shared__ int xidl[MAXB];
    __shared__ int cnt;
    __shared__ float hws[MAXB][NWAVE][17];  // +1 pad: stride 17 kills bank conflicts
    __shared__ float hl[MAXB][R];

    if (t == 0) cnt = 0;
    __syncthreads();
    // candidates with (i&3)==s: i = s + 4*t, t < 320 -- one probe per thread
    if (t < LB / NSPLIT) {
        const int i = s + NSPLIT * t;
        if (wids[i] == w) { int q = atomicAdd(&cnt, 1); if (q < MAXB) list[q] = i; }
    }
    __syncthreads();
    int n = cnt > MAXB ? MAXB : cnt;
    if (n == 0) return;
    if (t < n) xidl[t] = xids[list[t]];
    __syncthreads();

    // ---- phase 1: h[i][r] = x[xid_i] . A ----
    // lane owns d = 256*wave + (lane>>2) + 16k (k=0..15), r = 4*(lane&3)+c.
    // A load: af[1024*wave + 64k + lane] -> contiguous 1KB per wave
    const float4v* af = (const float4v*)(A + (size_t)w * D * R);
    float4v a[16];
    #pragma unroll
    for (int k = 0; k < 16; ++k) a[k] = af[1024 * wave + 64 * k + lane];

    const int dof = 256 * wave + (lane >> 2);
    for (int i = 0; i < n; ++i) {
        const float* xr = x + (size_t)xidl[i] * D + dof;
        float h0 = 0.f, h1 = 0.f, h2 = 0.f, h3 = 0.f;
        #pragma unroll
        for (int k = 0; k < 16; ++k) {
            const float xd = xr[16 * k];      // quad-broadcast, 64B/line per instr
            h0 += xd * a[k][0];
            h1 += xd * a[k][1];
            h2 += xd * a[k][2];
            h3 += xd * a[k][3];
        }
        // reduce over the 16 lane-groups sharing (lane&3)
        #pragma unroll
        for (int off = 4; off <= 32; off <<= 1) {
            h0 += __shfl_xor(h0, off, 64);
            h1 += __shfl_xor(h1, off, 64);
            h2 += __shfl_xor(h2, off, 64);
            h3 += __shfl_xor(h3, off, 64);
        }
        if (lane < 4) {                        // lane L holds r = 4L..4L+3
            hws[i][wave][4 * lane + 0] = h0;
            hws[i][wave][4 * lane + 1] = h1;
            hws[i][wave][4 * lane + 2] = h2;
            hws[i][wave][4 * lane + 3] = h3;
        }
    }
    __syncthreads();
    for (int idx = t; idx < n * R; idx += 1024) {
        const int i = idx >> 4, r = idx & 15;
        float sacc = 0.f;
        #pragma unroll
        for (int j = 0; j < NWAVE; ++j) sacc += hws[i][j][r];
        hl[i][r] = sacc;
    }
    __syncthreads();

    // ---- phase 2: y = 2*h.B ----
    const float* Bw = B + (size_t)w * R * D + 4 * t;
    float4v breg[R];
    #pragma unroll
    for (int r = 0; r < R; ++r) breg[r] = *(const float4v*)(Bw + (size_t)r * D);

    for (int i = 0; i < n; ++i) {
        const int b = list[i];
        float4v acc = {0.f, 0.f, 0.f, 0.f};
        #pragma unroll
        for (int r = 0; r < R; ++r) {
            const float hr = hl[i][r];         // LDS broadcast
            acc[0] += hr * breg[r][0];
            acc[1] += hr * breg[r][1];
            acc[2] += hr * breg[r][2];
            acc[3] += hr * breg[r][3];
        }
        #pragma unroll
        for (int k = 0; k < 4; ++k) acc[k] *= 2.0f;

        if (b < NBL * 4) {
            *(float4v*)(ybuf + (size_t)b * D + 4 * t) = acc;        // unique writer
        } else {
            *(float4v*)(out + (size_t)(NBL + (b - NBL * 4)) * D + 4 * t) = acc;
        }
    }
}

// ---------------- sum4: out[o] = ybuf[4o]+ybuf[4o+1]+ybuf[4o+2]+ybuf[4o+3] ---
__global__ __launch_bounds__(256) void sum4_kernel(
    const float* __restrict__ ybuf,
    float* __restrict__ out)
{
    const int o = blockIdx.x >> 2;            // 0..255
    const int q = blockIdx.x & 3;             // d-quarter
    const int col = q * 1024 + 4 * threadIdx.x;
    const float* y0 = ybuf + (size_t)(4 * o) * D + col;
    float4v v0 = *(const float4v*)(y0);
    float4v v1 = *(const float4v*)(y0 + D);
    float4v v2 = *(const float4v*)(y0 + 2 * D);
    float4v v3 = *(const float4v*)(y0 + 3 * D);
    float4v s;
    #pragma unroll
    for (int k = 0; k < 4; ++k) s[k] = (v0[k] + v1[k]) + (v2[k] + v3[k]);
    *(float4v*)(out + (size_t)o * D + col) = s;
}

extern "C" void kernel_launch(void* const* d_in, const int* in_sizes, int n_in,
                              void* d_out, int out_size, void* d_ws, size_t ws_size,
                              hipStream_t stream) {
    const float* x    = (const float*)d_in[0];
    const float* A    = (const float*)d_in[1];
    const float* B    = (const float*)d_in[2];
    const int*   xids = (const int*)d_in[3];
    const int*   wids = (const int*)d_in[4];
    float*       out  = (float*)d_out;

    float* ybuf = (float*)d_ws;   // [1024][4096] f32 = 16 MB

    hipLaunchKernelGGL(fused_kernel, dim3(NW * NSPLIT), dim3(1024), 0, stream,
                       x, A, B, xids, wids, ybuf, out);
    hipLaunchKernelGGL(sum4_kernel, dim3(NBL * 4), dim3(256), 0, stream,
                       ybuf, out);
}